// Round 1
// baseline (517.544 us; speedup 1.0000x reference)
//
#include <hip/hip_runtime.h>
#include <hip/hip_bf16.h>

// Problem constants
#define B_TOT  4096
#define M_TOT  65536
#define D_V    64
#define KD     96            // 64 (keys) + 32 (contexts)
#define BQ     64            // q rows per block (4 waves x 16)
#define BN     64            // keys per inner tile
#define NCHUNK 16
#define MC     (M_TOT / NCHUNK)   // 4096 keys per block
#define NQT    (B_TOT / BQ)       // 64
#define SP     72            // padded LDS row stride (bf16 elems), 144B = 16B-aligned

using short8  = __attribute__((ext_vector_type(8))) short;
using floatx4 = __attribute__((ext_vector_type(4))) float;

static __device__ __forceinline__ unsigned short f2bf(float f) {
  return __builtin_bit_cast(unsigned short, __float2bfloat16(f));
}

static __device__ __forceinline__ floatx4 mfma16(short8 a, short8 b, floatx4 c) {
  return __builtin_amdgcn_mfma_f32_16x16x32_bf16(a, b, c, 0, 0, 0);
}

// ---- prep kernels -----------------------------------------------------------

__global__ void prep_qc(const float* __restrict__ q, const float* __restrict__ ctx,
                        unsigned short* __restrict__ qc) {
  int t = blockIdx.x * 256 + threadIdx.x;      // 4096*96 total
  int b = t / KD, j = t % KD;
  float v = (j < 64) ? q[b * 64 + j] : 0.5f * ctx[b * 32 + (j - 64)];
  qc[t] = f2bf(v);
}

__global__ void prep_kc(const float* __restrict__ k, const float* __restrict__ c,
                        unsigned short* __restrict__ kc) {
  int t = blockIdx.x * 256 + threadIdx.x;      // 65536*96 total
  int m = t / KD, j = t % KD;
  float v = (j < 64) ? k[m * 64 + j] : c[m * 32 + (j - 64)];
  kc[t] = f2bf(v);
}

__global__ void prep_bias(const float* __restrict__ ts, const int* __restrict__ used,
                          float* __restrict__ bias) {
  int m = blockIdx.x * 256 + threadIdx.x;
  // fold the fixed softmax shift (-16) into the bias; masked slots -> -1e9
  bias[m] = used[m] ? (0.3f * __expf(-0.1f * (1.0f - ts[m])) - 16.0f) : -1e9f;
}

__global__ void prep_vt(const float* __restrict__ v, unsigned short* __restrict__ vt) {
  __shared__ float tile[64][65];
  int m0 = blockIdx.x * 64;
  int t = threadIdx.x;
#pragma unroll
  for (int i = 0; i < 16; ++i) {
    int idx = i * 256 + t;
    int r = idx >> 6, cc = idx & 63;
    tile[r][cc] = v[(size_t)(m0 + r) * 64 + cc];
  }
  __syncthreads();
#pragma unroll
  for (int i = 0; i < 16; ++i) {
    int idx = i * 256 + t;
    int d = idx >> 6, mm = idx & 63;
    vt[(size_t)d * M_TOT + m0 + mm] = f2bf(tile[mm][d]);
  }
}

// ---- flash attention main kernel -------------------------------------------
// grid (NQT, NCHUNK); block 256 = 4 waves, each wave owns 16 q-rows.
// Fixed-shift softmax: P = exp(S + bias - 16); partials combine linearly.

__global__ __launch_bounds__(256) void
flash_kernel(const unsigned short* __restrict__ qc,
             const unsigned short* __restrict__ kc,
             const unsigned short* __restrict__ vt,
             const float* __restrict__ bias,
             float* __restrict__ opart, float* __restrict__ lpart)
{
  __shared__ __align__(16) unsigned short pt[4][16][SP];  // per-wave P tiles
  const int qt    = blockIdx.x;
  const int chunk = blockIdx.y;
  const int tid   = threadIdx.x;
  const int w     = tid >> 6;
  const int lane  = tid & 63;
  const int lq    = lane >> 4;   // quad
  const int lc    = lane & 15;

  floatx4 zero; zero[0] = 0.f; zero[1] = 0.f; zero[2] = 0.f; zero[3] = 0.f;

  // Q fragments (A-layout: m=lc, k = ks*32 + lq*8 + j), contiguous 16B loads
  const int qrow = qt * BQ + w * 16 + lc;
  const short8* qrp = reinterpret_cast<const short8*>(qc + (size_t)qrow * KD);
  short8 qf0 = qrp[lq];
  short8 qf1 = qrp[4 + lq];
  short8 qf2 = qrp[8 + lq];

  short8 ones;
#pragma unroll
  for (int i = 0; i < 8; ++i) ones[i] = (short)0x3F80;  // bf16 1.0

  const int n0base = chunk * MC;
  const short8* kp[4];
  const short8* vp[4];
#pragma unroll
  for (int nt = 0; nt < 4; ++nt)
    kp[nt] = reinterpret_cast<const short8*>(kc + (size_t)(n0base + nt * 16 + lc) * KD);
#pragma unroll
  for (int nd = 0; nd < 4; ++nd)
    vp[nd] = reinterpret_cast<const short8*>(vt + (size_t)(nd * 16 + lc) * M_TOT + n0base);
  const float* bp = bias + n0base + lc;

  floatx4 o0 = zero, o1 = zero, o2 = zero, o3 = zero;
  floatx4 lacc = zero;

  for (int it = 0; it < MC / BN; ++it) {
    // S = Q * K^T  (B-frag = contiguous row of Kc)
    floatx4 s[4];
#pragma unroll
    for (int nt = 0; nt < 4; ++nt) {
      floatx4 acc = zero;
      acc = mfma16(qf0, kp[nt][lq],     acc);
      acc = mfma16(qf1, kp[nt][4 + lq], acc);
      acc = mfma16(qf2, kp[nt][8 + lq], acc);
      s[nt] = acc;
    }
    // P = exp(S + bias') -> bf16 -> LDS (C-layout: row = lq*4+r, col = nt*16+lc)
#pragma unroll
    for (int nt = 0; nt < 4; ++nt) {
      float badj = bp[nt * 16];
#pragma unroll
      for (int r = 0; r < 4; ++r) {
        float p = __expf(s[nt][r] + badj);
        pt[w][lq * 4 + r][nt * 16 + lc] = f2bf(p);
      }
    }
    // P back out in A-layout (row = lc, k contiguous); same-wave DS ordering
    short8 pa0 = *reinterpret_cast<const short8*>(&pt[w][lc][lq * 8]);
    short8 pa1 = *reinterpret_cast<const short8*>(&pt[w][lc][32 + lq * 8]);
    // row sums via ones-MFMA
    lacc = mfma16(pa0, ones, lacc);
    lacc = mfma16(pa1, ones, lacc);
    // O += P * V (B-frag = contiguous run of a Vt row)
    o0 = mfma16(pa0, vp[0][lq], o0);  o0 = mfma16(pa1, vp[0][4 + lq], o0);
    o1 = mfma16(pa0, vp[1][lq], o1);  o1 = mfma16(pa1, vp[1][4 + lq], o1);
    o2 = mfma16(pa0, vp[2][lq], o2);  o2 = mfma16(pa1, vp[2][4 + lq], o2);
    o3 = mfma16(pa0, vp[3][lq], o3);  o3 = mfma16(pa1, vp[3][4 + lq], o3);
    // advance pointers
#pragma unroll
    for (int nt = 0; nt < 4; ++nt) kp[nt] += (BN * KD) / 8;
#pragma unroll
    for (int nd = 0; nd < 4; ++nd) vp[nd] += BN / 8;
    bp += BN;
  }

  // epilogue: write partial O and l
  const int pb = qt * NCHUNK + chunk;
  float* op = opart + (size_t)pb * BQ * D_V;
  const int rbase = w * 16 + lq * 4;
  floatx4 oo[4] = {o0, o1, o2, o3};
#pragma unroll
  for (int nd = 0; nd < 4; ++nd)
#pragma unroll
    for (int r = 0; r < 4; ++r)
      op[(rbase + r) * D_V + nd * 16 + lc] = oo[nd][r];
  if (lc == 0) {
    float* lp = lpart + (size_t)pb * BQ;
#pragma unroll
    for (int r = 0; r < 4; ++r) lp[rbase + r] = lacc[r];
  }
}

// ---- final reduction --------------------------------------------------------

__global__ void reduce_out(const float* __restrict__ opart, const float* __restrict__ lpart,
                           float* __restrict__ out) {
  int t = blockIdx.x * 256 + threadIdx.x;   // 262144 total
  int b = t >> 6, d = t & 63;
  int qt = b >> 6, r = b & 63;
  float os = 0.f, ls = 0.f;
#pragma unroll
  for (int c = 0; c < NCHUNK; ++c) {
    os += opart[((size_t)(qt * NCHUNK + c) * BQ + r) * D_V + d];
    ls += lpart[(size_t)(qt * NCHUNK + c) * BQ + r];
  }
  out[t] = os / ls;
}

// ---- launcher ---------------------------------------------------------------

extern "C" void kernel_launch(void* const* d_in, const int* in_sizes, int n_in,
                              void* d_out, int out_size, void* d_ws, size_t ws_size,
                              hipStream_t stream) {
  const float* query    = (const float*)d_in[0];
  const float* context  = (const float*)d_in[1];
  const float* keys     = (const float*)d_in[2];
  const float* values   = (const float*)d_in[3];
  const float* contexts = (const float*)d_in[4];
  const float* ts       = (const float*)d_in[5];
  const int*   used     = (const int*)d_in[6];
  float* out = (float*)d_out;

  char* ws = (char*)d_ws;
  unsigned short* qc = (unsigned short*)ws;  ws += (size_t)B_TOT * KD * 2;      // 768 KB
  unsigned short* kc = (unsigned short*)ws;  ws += (size_t)M_TOT * KD * 2;      // 12 MB
  unsigned short* vt = (unsigned short*)ws;  ws += (size_t)D_V * M_TOT * 2;     // 8 MB
  float* bias  = (float*)ws;                 ws += (size_t)M_TOT * 4;           // 256 KB
  float* opart = (float*)ws;                 ws += (size_t)NQT * NCHUNK * BQ * D_V * 4; // 16 MB
  float* lpart = (float*)ws;                 ws += (size_t)NQT * NCHUNK * BQ * 4;

  prep_qc  <<<(B_TOT * KD) / 256, 256, 0, stream>>>(query, context, qc);
  prep_kc  <<<(M_TOT * KD) / 256, 256, 0, stream>>>(keys, contexts, kc);
  prep_bias<<<M_TOT / 256,        256, 0, stream>>>(ts, used, bias);
  prep_vt  <<<M_TOT / 64,         256, 0, stream>>>(values, vt);

  dim3 grid(NQT, NCHUNK);
  flash_kernel<<<grid, 256, 0, stream>>>(qc, kc, vt, bias, opart, lpart);

  reduce_out<<<(B_TOT * D_V) / 256, 256, 0, stream>>>(opart, lpart, out);
}